// Round 1
// baseline (305.067 us; speedup 1.0000x reference)
//
#include <hip/hip_runtime.h>

namespace {

constexpr int T  = 1024;
constexpr int C  = 512;
constexpr int NH = 8;
constexpr int DH = 64;

// ---------------------------------------------------------------------------
// GEMM: Y[b,o,t] = sum_c W[o,c] * X[b,c,t] + bias[o]
// ATT_IN=false: X is [B,C,T] (natural). ATT_IN=true: X is [B,H,T,64].
// 64x64 tile, BK=32, 256 threads, 4x4 micro-tile per thread.
// ---------------------------------------------------------------------------
template <bool ATT_IN>
__global__ __launch_bounds__(256) void proj_gemm(
    const float* __restrict__ W, const float* __restrict__ bias,
    const float* __restrict__ X, float* __restrict__ Y) {
  __shared__ float As[32][68];  // As[c][o]
  __shared__ float Bs[32][68];  // Bs[c][t]
  const int b  = blockIdx.z;
  const int o0 = blockIdx.y * 64;
  const int t0 = blockIdx.x * 64;
  const int tid = threadIdx.x;
  const int tx = tid & 15;
  const int ty = tid >> 4;
  float acc[4][4] = {};

  for (int c0 = 0; c0 < C; c0 += 32) {
    __syncthreads();
    {  // A tile: W[o0+r][c0+cc] -> As[cc][r]   (coalesced f4 read along c)
      const int r  = tid >> 3;
      const int cc = (tid & 7) << 2;
#pragma unroll
      for (int p = 0; p < 2; ++p) {
        const float4 a = *reinterpret_cast<const float4*>(
            &W[(size_t)(o0 + r + p * 32) * C + c0 + cc]);
        As[cc + 0][r + p * 32] = a.x;
        As[cc + 1][r + p * 32] = a.y;
        As[cc + 2][r + p * 32] = a.z;
        As[cc + 3][r + p * 32] = a.w;
      }
    }
    if (!ATT_IN) {  // x: natural [c][t], straight f4 copy
      const int cc = tid >> 4;
      const int tt = (tid & 15) << 2;
#pragma unroll
      for (int p = 0; p < 2; ++p) {
        *reinterpret_cast<float4*>(&Bs[cc + p * 16][tt]) =
            *reinterpret_cast<const float4*>(
                &X[((size_t)b * C + c0 + cc + p * 16) * T + t0 + tt]);
      }
    } else {  // att: [B,H,T,64]; c = h*64+dd; tile spans one h (c0 % 32 == 0)
      const int tt  = tid >> 3;
      const int cc  = (tid & 7) << 2;
      const int h   = c0 >> 6;
      const int ddb = c0 & 63;
#pragma unroll
      for (int p = 0; p < 2; ++p) {
        const float4 v = *reinterpret_cast<const float4*>(
            &X[(((size_t)b * NH + h) * T + t0 + tt + p * 32) * DH + ddb + cc]);
        Bs[cc + 0][tt + p * 32] = v.x;
        Bs[cc + 1][tt + p * 32] = v.y;
        Bs[cc + 2][tt + p * 32] = v.z;
        Bs[cc + 3][tt + p * 32] = v.w;
      }
    }
    __syncthreads();
#pragma unroll
    for (int c = 0; c < 32; ++c) {
      const float4 a4 = *reinterpret_cast<const float4*>(&As[c][ty << 2]);
      const float4 b4 = *reinterpret_cast<const float4*>(&Bs[c][tx << 2]);
      const float av[4] = {a4.x, a4.y, a4.z, a4.w};
      const float bv[4] = {b4.x, b4.y, b4.z, b4.w};
#pragma unroll
      for (int i = 0; i < 4; ++i)
#pragma unroll
        for (int j = 0; j < 4; ++j) acc[i][j] += av[i] * bv[j];
    }
  }
#pragma unroll
  for (int i = 0; i < 4; ++i) {
    const int o = o0 + (ty << 2) + i;
    const float bo = bias[o];
    float4 r;
    r.x = acc[i][0] + bo;
    r.y = acc[i][1] + bo;
    r.z = acc[i][2] + bo;
    r.w = acc[i][3] + bo;
    *reinterpret_cast<float4*>(&Y[((size_t)b * C + o) * T + t0 + (tx << 2)]) = r;
  }
}

// ---------------------------------------------------------------------------
// Flash-style attention with relative-position K/V windows.
// Q,K,V in [B,C,T] layout (c = h*64+dd). One block = one (b,h) x 64 q-rows.
// Output O in [B,H,T,64].
// ---------------------------------------------------------------------------
__global__ __launch_bounds__(256) void attn_kernel(
    const float* __restrict__ Q, const float* __restrict__ K,
    const float* __restrict__ V, const int* __restrict__ mask,
    const float* __restrict__ ek, const float* __restrict__ ev,
    float* __restrict__ O) {
  __shared__ float Qst[64][64];  // [dd][t]   natural layout, b128 reads
  __shared__ float Kst[64][64];  // [dd][s]
  __shared__ float Vs[64][68];   // [s][dd]   pitch 68 -> aligned b128, 2-way
  __shared__ float Ps[64][68];   // [t][s]
  __shared__ float rk[64][12];   // rk[t][w] = Q[t].ek[w] / 8
  __shared__ float eks[9][64];
  __shared__ float evs[9][64];
  __shared__ int msk[64];

  const int b  = blockIdx.z;
  const int h  = blockIdx.y;
  const int t0 = blockIdx.x * 64;
  const int tid = threadIdx.x;
  const int tx = tid & 15;  // s / dd micro dim
  const int ty = tid >> 4;  // t micro dim

  const float* Qb = Q + ((size_t)b * C + h * DH) * T + t0;
  const float* Kb = K + ((size_t)b * C + h * DH) * T;
  const float* Vb = V + ((size_t)b * C + h * DH) * T;

  {  // Q tile [dd][t], straight f4 copy
    const int dd = tid >> 4;
    const int tt = (tid & 15) << 2;
#pragma unroll
    for (int p = 0; p < 4; ++p) {
      *reinterpret_cast<float4*>(&Qst[dd + p * 16][tt]) =
          *reinterpret_cast<const float4*>(&Qb[(size_t)(dd + p * 16) * T + tt]);
    }
  }
  if (tid < 144) {  // 9*64 floats = 144 float4 each
    reinterpret_cast<float4*>(&eks[0][0])[tid] =
        reinterpret_cast<const float4*>(ek)[tid];
    reinterpret_cast<float4*>(&evs[0][0])[tid] =
        reinterpret_cast<const float4*>(ev)[tid];
  }
  __syncthreads();
  // rk[r][w] = 0.125 * sum_dd Q[t0+r][dd] * ek[w][dd]
  for (int task = tid; task < 576; task += 256) {
    const int r = task / 9;
    const int w = task - r * 9;
    float s = 0.f;
    for (int dd = 0; dd < 64; ++dd) s += Qst[dd][r] * eks[w][dd];
    rk[r][w] = 0.125f * s;
  }

  float m[4], l[4], acc[4][4] = {};
#pragma unroll
  for (int i = 0; i < 4; ++i) {
    m[i] = -1e30f;
    l[i] = 0.f;
  }

  for (int st = 0; st < 16; ++st) {
    const int s0 = st * 64;
    __syncthreads();  // prev-iter Ps/Vs/Kst reads done; rk visible at st=0
    {
      const int dd = tid >> 4;
      const int ss = (tid & 15) << 2;
#pragma unroll
      for (int p = 0; p < 4; ++p) {
        *reinterpret_cast<float4*>(&Kst[dd + p * 16][ss]) =
            *reinterpret_cast<const float4*>(
                &Kb[(size_t)(dd + p * 16) * T + s0 + ss]);
        const float4 v = *reinterpret_cast<const float4*>(
            &Vb[(size_t)(dd + p * 16) * T + s0 + ss]);
        Vs[ss + 0][dd + p * 16] = v.x;
        Vs[ss + 1][dd + p * 16] = v.y;
        Vs[ss + 2][dd + p * 16] = v.z;
        Vs[ss + 3][dd + p * 16] = v.w;
      }
      if (tid < 64) msk[tid] = mask[b * T + s0 + tid];
    }
    __syncthreads();

    // S = Q K^T / 8
    float sv[4][4] = {};
#pragma unroll
    for (int dd = 0; dd < 64; ++dd) {
      const float4 q4 = *reinterpret_cast<const float4*>(&Qst[dd][ty << 2]);
      const float4 k4 = *reinterpret_cast<const float4*>(&Kst[dd][tx << 2]);
      const float qv[4] = {q4.x, q4.y, q4.z, q4.w};
      const float kv[4] = {k4.x, k4.y, k4.z, k4.w};
#pragma unroll
      for (int i = 0; i < 4; ++i)
#pragma unroll
        for (int j = 0; j < 4; ++j) sv[i][j] += qv[i] * kv[j];
    }
#pragma unroll
    for (int i = 0; i < 4; ++i)
#pragma unroll
      for (int j = 0; j < 4; ++j) sv[i][j] *= 0.125f;

    // relative-K window: S[t,s] += rk[t][s-t+4] for |s-t|<=4
    if (s0 >= t0 - 64 && s0 <= t0 + 64) {
#pragma unroll
      for (int i = 0; i < 4; ++i) {
        const int ta = t0 + (ty << 2) + i;
#pragma unroll
        for (int j = 0; j < 4; ++j) {
          const int sd = s0 + (tx << 2) + j - ta;
          if (sd >= -4 && sd <= 4) sv[i][j] += rk[(ty << 2) + i][sd + 4];
        }
      }
    }
#pragma unroll
    for (int j = 0; j < 4; ++j) {
      if (msk[(tx << 2) + j] == 0) {
#pragma unroll
        for (int i = 0; i < 4; ++i) sv[i][j] = -10000.0f;
      }
    }

    // online softmax (row reduce over the 16 tx lanes of each 16-lane group)
#pragma unroll
    for (int i = 0; i < 4; ++i) {
      float rmax = fmaxf(fmaxf(sv[i][0], sv[i][1]), fmaxf(sv[i][2], sv[i][3]));
#pragma unroll
      for (int off = 1; off < 16; off <<= 1)
        rmax = fmaxf(rmax, __shfl_xor(rmax, off));
      const float mnew = fmaxf(m[i], rmax);
      const float corr = __expf(m[i] - mnew);
      float rsum = 0.f;
#pragma unroll
      for (int j = 0; j < 4; ++j) {
        sv[i][j] = __expf(sv[i][j] - mnew);
        rsum += sv[i][j];
      }
#pragma unroll
      for (int off = 1; off < 16; off <<= 1) rsum += __shfl_xor(rsum, off);
      l[i] = l[i] * corr + rsum;
      m[i] = mnew;
#pragma unroll
      for (int j = 0; j < 4; ++j) acc[i][j] *= corr;
    }
#pragma unroll
    for (int i = 0; i < 4; ++i) {
      float4 p4;
      p4.x = sv[i][0];
      p4.y = sv[i][1];
      p4.z = sv[i][2];
      p4.w = sv[i][3];
      *reinterpret_cast<float4*>(&Ps[(ty << 2) + i][tx << 2]) = p4;
    }
    __syncthreads();

    // O += P V  (Vs b128 over dd; Ps broadcast scalar)
#pragma unroll 4
    for (int s = 0; s < 64; ++s) {
      const float4 v4 = *reinterpret_cast<const float4*>(&Vs[s][tx << 2]);
#pragma unroll
      for (int i = 0; i < 4; ++i) {
        const float p = Ps[(ty << 2) + i][s];
        acc[i][0] += p * v4.x;
        acc[i][1] += p * v4.y;
        acc[i][2] += p * v4.z;
        acc[i][3] += p * v4.w;
      }
    }
    // relative-V window: O[t] += sum_w P[t, t-4+w] * ev[w]
#pragma unroll
    for (int i = 0; i < 4; ++i) {
      const int ta = t0 + (ty << 2) + i;
#pragma unroll
      for (int w = 0; w < 9; ++w) {
        const int sr = ta - 4 + w - s0;
        if (sr >= 0 && sr < 64) {
          const float p = Ps[(ty << 2) + i][sr];
          const float4 e4 = *reinterpret_cast<const float4*>(&evs[w][tx << 2]);
          acc[i][0] += p * e4.x;
          acc[i][1] += p * e4.y;
          acc[i][2] += p * e4.z;
          acc[i][3] += p * e4.w;
        }
      }
    }
  }

#pragma unroll
  for (int i = 0; i < 4; ++i) {
    const float inv = 1.0f / l[i];
    float4 r;
    r.x = acc[i][0] * inv;
    r.y = acc[i][1] * inv;
    r.z = acc[i][2] * inv;
    r.w = acc[i][3] * inv;
    *reinterpret_cast<float4*>(
        &O[(((size_t)b * NH + h) * T + t0 + (ty << 2) + i) * DH + (tx << 2)]) = r;
  }
}

}  // namespace

extern "C" void kernel_launch(void* const* d_in, const int* in_sizes, int n_in,
                              void* d_out, int out_size, void* d_ws,
                              size_t ws_size, hipStream_t stream) {
  const float* x    = (const float*)d_in[0];
  const int*   mask = (const int*)d_in[1];
  const float* Wq   = (const float*)d_in[2];
  const float* bq   = (const float*)d_in[3];
  const float* Wk   = (const float*)d_in[4];
  const float* bk   = (const float*)d_in[5];
  const float* Wv   = (const float*)d_in[6];
  const float* bv   = (const float*)d_in[7];
  const float* Wo   = (const float*)d_in[8];
  const float* bo   = (const float*)d_in[9];
  const float* ek   = (const float*)d_in[10];
  const float* ev   = (const float*)d_in[11];
  float* out = (float*)d_out;
  float* ws  = (float*)d_ws;

  const size_t mat = (size_t)4 * C * T;  // 2M floats per [B,C,T] matrix
  float* q   = ws;
  float* k   = ws + mat;
  float* v   = ws + 2 * mat;
  float* att = ws + 3 * mat;  // [B,H,T,64]

  dim3 blk(256);
  dim3 g(16, 8, 4);  // (t-tiles, o-tiles, b)
  proj_gemm<false><<<g, blk, 0, stream>>>(Wq, bq, x, q);
  proj_gemm<false><<<g, blk, 0, stream>>>(Wk, bk, x, k);
  proj_gemm<false><<<g, blk, 0, stream>>>(Wv, bv, x, v);
  attn_kernel<<<dim3(16, 8, 4), blk, 0, stream>>>(q, k, v, mask, ek, ev, att);
  proj_gemm<true><<<g, blk, 0, stream>>>(Wo, bo, att, out);
}

// Round 2
// 99.706 us; speedup vs baseline: 3.0597x; 3.0597x over previous
//
#include <hip/hip_runtime.h>

typedef unsigned short u16;
typedef unsigned int u32;
using f32x4 = __attribute__((ext_vector_type(4))) float;
using s16x8 = __attribute__((ext_vector_type(8))) short;
using u16x4 = __attribute__((ext_vector_type(4))) unsigned short;
using u16x8 = __attribute__((ext_vector_type(8))) unsigned short;

namespace {

constexpr int T = 1024;
constexpr int C = 512;

__device__ inline u16 f2bf(float f) {
  u32 u = __builtin_bit_cast(u32, f);
  u32 r = (u + 0x7fffu + ((u >> 16) & 1u)) >> 16;
  return (u16)r;
}
__device__ inline float bf2f(u16 v) {
  return __builtin_bit_cast(float, (u32)v << 16);
}
__device__ inline f32x4 mfma16(s16x8 a, s16x8 b, f32x4 c) {
  return __builtin_amdgcn_mfma_f32_16x16x32_bf16(a, b, c, 0, 0, 0);
}

// ---------------------------------------------------------------------------
// fp32 -> bf16 conversion: x (2048 blocks) then Wq/Wk/Wv/Wo (256 blocks each)
// ---------------------------------------------------------------------------
__global__ __launch_bounds__(256) void convert_all(
    const float* __restrict__ x, const float* __restrict__ Wq,
    const float* __restrict__ Wk, const float* __restrict__ Wv,
    const float* __restrict__ Wo, u16* __restrict__ xb, u16* __restrict__ Wqb,
    u16* __restrict__ Wkb, u16* __restrict__ Wvb, u16* __restrict__ Wob) {
  const int tid = threadIdx.x;
  const int bid = blockIdx.x;
  const float* src;
  u16* dst;
  size_t off;
  if (bid < 2048) {
    src = x; dst = xb;
    off = ((size_t)bid * 256 + tid) * 4;
  } else {
    const int j = bid - 2048;
    const int w = j >> 8;
    src = w == 0 ? Wq : w == 1 ? Wk : w == 2 ? Wv : Wo;
    dst = w == 0 ? Wqb : w == 1 ? Wkb : w == 2 ? Wvb : Wob;
    off = (((size_t)(j & 255)) * 256 + tid) * 4;
  }
  const float4 v = *reinterpret_cast<const float4*>(src + off);
  u16x4 o;
  o[0] = f2bf(v.x); o[1] = f2bf(v.y); o[2] = f2bf(v.z); o[3] = f2bf(v.w);
  *reinterpret_cast<u16x4*>(dst + off) = o;
}

// ---------------------------------------------------------------------------
// Fused q/k/v projection GEMM (bf16 MFMA).  Y[o][t] = sum_c W[o][c] x[c][t].
// A = W direct-global b128 frags; B = x^T staged in LDS (XOR swizzle, dbuf).
// Block tile 64o x 128t, 4 waves (2x2), wave tile 32o x 64t, BK = 32.
// wsel 0(q)/1(k): out [b][h][t][dd] bf16.  wsel 2(v): out [b][h][dd][t] bf16.
// ---------------------------------------------------------------------------
__global__ __launch_bounds__(256) void qkv_gemm(
    const u16* __restrict__ xb, const u16* __restrict__ Wqb,
    const u16* __restrict__ Wkb, const u16* __restrict__ Wvb,
    const float* __restrict__ bq, const float* __restrict__ bk,
    const float* __restrict__ bv, u16* __restrict__ qb, u16* __restrict__ kb,
    u16* __restrict__ vb) {
  __shared__ u16 Bs[2][128 * 32];
  __shared__ float sbias[64];
  const int tid = threadIdx.x;
  const int z = blockIdx.z;
  const int b = z / 3, wsel = z - 3 * b;
  const u16* W = wsel == 0 ? Wqb : wsel == 1 ? Wkb : Wvb;
  const float* bias = wsel == 0 ? bq : wsel == 1 ? bk : bv;
  const int o0 = blockIdx.y * 64;
  const int t0 = blockIdx.x * 128;
  if (tid < 16)
    *reinterpret_cast<float4*>(&sbias[tid * 4]) =
        *reinterpret_cast<const float4*>(&bias[o0 + tid * 4]);

  const int l = tid & 63, wid = tid >> 6;
  const int wm = wid >> 1, wn = wid & 1;
  const int lr = l & 15, lg = l >> 4;

  // staging map: thread -> (c-pair, t-group of 8)
  const int cpair = tid & 15, tgrp = tid >> 4;
  const u16* xrow =
      xb + ((size_t)(b * C) + 2 * cpair) * T + t0 + 8 * tgrp;

  const u16* Arow0 = W + (size_t)(o0 + 32 * wm + lr) * C + 8 * lg;
  const u16* Arow1 = Arow0 + 16 * C;

  f32x4 acc[2][4] = {};

  auto stage = [&](int kk, int buf) {
    const u16* p = xrow + (size_t)kk * 32 * T;
    const u16x8 v0 = *reinterpret_cast<const u16x8*>(p);
    const u16x8 v1 = *reinterpret_cast<const u16x8*>(p + T);
    char* base = (char*)&Bs[buf][0];
#pragma unroll
    for (int j = 0; j < 8; ++j) {
      const int t = 8 * tgrp + j;
      const u32 w2 = (u32)v0[j] | ((u32)v1[j] << 16);
      *(u32*)(base + ((t * 64 + 4 * cpair) ^ ((t & 3) << 4))) = w2;
    }
  };

  s16x8 a0 = *reinterpret_cast<const s16x8*>(Arow0);
  s16x8 a1 = *reinterpret_cast<const s16x8*>(Arow1);
  stage(0, 0);
  __syncthreads();

  for (int kk = 0; kk < 16; ++kk) {
    s16x8 an0, an1;
    if (kk < 15) {
      an0 = *reinterpret_cast<const s16x8*>(Arow0 + (kk + 1) * 32);
      an1 = *reinterpret_cast<const s16x8*>(Arow1 + (kk + 1) * 32);
      stage(kk + 1, (kk + 1) & 1);
    }
    const char* rb = (const char*)&Bs[kk & 1][0];
#pragma unroll
    for (int nf = 0; nf < 4; ++nf) {
      const int t = 64 * wn + 16 * nf + lr;
      const s16x8 bfrag = *reinterpret_cast<const s16x8*>(
          rb + ((t * 64 + 16 * lg) ^ ((t & 3) << 4)));
      acc[0][nf] = mfma16(a0, bfrag, acc[0][nf]);
      acc[1][nf] = mfma16(a1, bfrag, acc[1][nf]);
    }
    __syncthreads();
    if (kk < 15) { a0 = an0; a1 = an1; }
  }

  const int h = o0 >> 6;
  if (wsel < 2) {
    u16* dst = (wsel == 0) ? qb : kb;
#pragma unroll
    for (int m = 0; m < 2; ++m) {
      const int ob = 32 * wm + 16 * m + 4 * lg;  // local o (== dd), 4-aligned
#pragma unroll
      for (int nf = 0; nf < 4; ++nf) {
        const int t = t0 + 64 * wn + 16 * nf + lr;
        u16x4 pk;
#pragma unroll
        for (int r = 0; r < 4; ++r) pk[r] = f2bf(acc[m][nf][r] + sbias[ob + r]);
        *reinterpret_cast<u16x4*>(
            &dst[((size_t)((b * 8 + h) * T) + t) * 64 + ob]) = pk;
      }
    }
  } else {
#pragma unroll
    for (int m = 0; m < 2; ++m) {
      const int ob = 32 * wm + 16 * m + 4 * lg;
#pragma unroll
      for (int nf = 0; nf < 4; ++nf) {
        const int t = t0 + 64 * wn + 16 * nf + lr;
#pragma unroll
        for (int r = 0; r < 4; ++r)
          vb[((size_t)((b * 8 + h) * 64) + ob + r) * T + t] =
              f2bf(acc[m][nf][r] + sbias[ob + r]);
      }
    }
  }
}

// ---------------------------------------------------------------------------
// MFMA flash attention with relative-position windows.
// Block = (b, h, 64-t chunk); 4 waves, each owns a 16-t strip.
// q,k: [b][h][t][64] bf16 ; v: [b][h][64][t] bf16 ; out att: [b][h][t][64].
// ---------------------------------------------------------------------------
__global__ __launch_bounds__(256) void attn_mfma(
    const u16* __restrict__ qb, const u16* __restrict__ kb,
    const u16* __restrict__ vb, const int* __restrict__ mask,
    const float* __restrict__ ek, const float* __restrict__ ev,
    u16* __restrict__ attb) {
  __shared__ u16 Qs[64 * 64];       // rows t (128B), XOR-swizzled
  __shared__ u16 Ks[64 * 64];       // rows s
  __shared__ u16 Vs[64 * 64];       // rows dd
  __shared__ float Ps[4][16 * 68];  // per-wave P~ fp32, pitch 68
  __shared__ float rkk[64][12];
  __shared__ float eks[9][64];
  __shared__ float evs[9][64];
  __shared__ int msk[64];

  const int b = blockIdx.z, h = blockIdx.y, tc = blockIdx.x * 64;
  const int tid = threadIdx.x;
  const int l = tid & 63, wid = tid >> 6;
  const int lr = l & 15, lg = l >> 4;

  const size_t bh = (size_t)(b * 8 + h);
  const u16* qrow = qb + (bh * T + tc) * 64;
  const u16* krow = kb + bh * T * 64;
  const u16* vrow = vb + bh * 64 * T;

  {  // stage Q (swizzled b128)
    char* qs = (char*)Qs;
#pragma unroll
    for (int rep = 0; rep < 2; ++rep) {
      const int idx = rep * 256 + tid;
      const int t = idx >> 3, slot = idx & 7;
      const u16x8 v =
          *reinterpret_cast<const u16x8*>(&qrow[(size_t)t * 64 + 8 * slot]);
      *(u16x8*)(qs + ((t * 128 + 16 * slot) ^ ((t & 7) << 4))) = v;
    }
  }
  if (tid < 144) {
    reinterpret_cast<float4*>(&eks[0][0])[tid] =
        reinterpret_cast<const float4*>(ek)[tid];
    reinterpret_cast<float4*>(&evs[0][0])[tid] =
        reinterpret_cast<const float4*>(ev)[tid];
  }
  __syncthreads();

  {  // rk[t][w] = 0.125 * Q[t].ek[w]
    const char* qs = (const char*)Qs;
    for (int task = tid; task < 576; task += 256) {
      const int r = task / 9, w = task - 9 * r;
      float s = 0.f;
      const float* er = &eks[w][0];
#pragma unroll 8
      for (int dd = 0; dd < 64; ++dd) {
        const u16 qv = *(const u16*)(qs + ((r * 128 + 2 * dd) ^ ((r & 7) << 4)));
        s += bf2f(qv) * er[dd];
      }
      rkk[r][w] = 0.125f * s;
    }
  }

  float m[4], lsum[4];
  f32x4 Oa[4] = {};
#pragma unroll
  for (int r = 0; r < 4; ++r) { m[r] = -1e30f; lsum[r] = 0.f; }

  // Q A-frags for this wave's 16-t strip (stable for the whole kernel)
  const int tA = 16 * wid + lr;
  s16x8 aq0, aq1;
  {
    const char* qs = (const char*)Qs;
    aq0 = *reinterpret_cast<const s16x8*>(
        qs + ((tA * 128 + 16 * lg) ^ ((tA & 7) << 4)));
    aq1 = *reinterpret_cast<const s16x8*>(
        qs + ((tA * 128 + 16 * (lg + 4)) ^ ((tA & 7) << 4)));
  }

  for (int st = 0; st < 16; ++st) {
    const int s0 = st * 64;
    __syncthreads();
    {
      char* ks_ = (char*)Ks;
      char* vs_ = (char*)Vs;
#pragma unroll
      for (int rep = 0; rep < 2; ++rep) {
        const int idx = rep * 256 + tid;
        const int rrow = idx >> 3, slot = idx & 7;
        const u16x8 kv = *reinterpret_cast<const u16x8*>(
            &krow[(size_t)(s0 + rrow) * 64 + 8 * slot]);
        *(u16x8*)(ks_ + ((rrow * 128 + 16 * slot) ^ ((rrow & 7) << 4))) = kv;
        const u16x8 vv = *reinterpret_cast<const u16x8*>(
            &vrow[(size_t)rrow * T + s0 + 8 * slot]);
        *(u16x8*)(vs_ + ((rrow * 128 + 16 * slot) ^ ((rrow & 7) << 4))) = vv;
      }
      if (tid < 64) msk[tid] = mask[b * T + s0 + tid];
    }
    __syncthreads();

    // S = Q K^T (two K-steps of 32 dd)
    f32x4 S[4] = {};
    const char* ksb = (const char*)Ks;
#pragma unroll
    for (int nf = 0; nf < 4; ++nf) {
      const int srow = 16 * nf + lr;
      const int swz = (srow & 7) << 4;
      const s16x8 bk0 = *reinterpret_cast<const s16x8*>(
          ksb + ((srow * 128 + 16 * lg) ^ swz));
      S[nf] = mfma16(aq0, bk0, S[nf]);
      const s16x8 bk1 = *reinterpret_cast<const s16x8*>(
          ksb + ((srow * 128 + 16 * (lg + 4)) ^ swz));
      S[nf] = mfma16(aq1, bk1, S[nf]);
    }

    const bool diag = (s0 <= tc + 67) && (s0 + 63 >= tc - 4);

    // scale + rel-k + mask
#pragma unroll
    for (int nf = 0; nf < 4; ++nf) {
      const int sl_ = 16 * nf + lr;
      const int mz = msk[sl_];
#pragma unroll
      for (int r = 0; r < 4; ++r) {
        const int tl = 16 * wid + 4 * lg + r;
        float v = S[nf][r] * 0.125f;
        if (diag) {
          const int sd = (s0 + sl_) - (tc + tl);
          if (sd >= -4 && sd <= 4) v += rkk[tl][sd + 4];
        }
        S[nf][r] = (mz == 0) ? -10000.0f : v;
      }
    }

    // online softmax (rows t = 4*lg + r within strip; reduce over 16 lanes)
    float pex[4][4], corr[4];
#pragma unroll
    for (int r = 0; r < 4; ++r) {
      float rm = fmaxf(fmaxf(S[0][r], S[1][r]), fmaxf(S[2][r], S[3][r]));
#pragma unroll
      for (int off = 1; off < 16; off <<= 1) rm = fmaxf(rm, __shfl_xor(rm, off));
      const float mn = fmaxf(m[r], rm);
      corr[r] = __expf(m[r] - mn);
      m[r] = mn;
      float rs = 0.f;
#pragma unroll
      for (int nf = 0; nf < 4; ++nf) {
        const float p = __expf(S[nf][r] - mn);
        pex[nf][r] = p;
        rs += p;
      }
#pragma unroll
      for (int off = 1; off < 16; off <<= 1) rs += __shfl_xor(rs, off);
      lsum[r] = lsum[r] * corr[r] + rs;
    }
#pragma unroll
    for (int nf = 0; nf < 4; ++nf) {
      f32x4 o = Oa[nf];
      o[0] *= corr[0]; o[1] *= corr[1]; o[2] *= corr[2]; o[3] *= corr[3];
      Oa[nf] = o;
#pragma unroll
      for (int r = 0; r < 4; ++r)
        Ps[wid][(4 * lg + r) * 68 + 16 * nf + lr] = pex[nf][r];
    }

    // O += P~ V   (A-frag from Ps fp32 -> bf16; B-frag from Vs)
    const char* vsb = (const char*)Vs;
#pragma unroll
    for (int ks = 0; ks < 2; ++ks) {
      const float* prow = &Ps[wid][lr * 68 + 8 * lg + 32 * ks];
      const float4 p0 = *reinterpret_cast<const float4*>(prow);
      const float4 p1 = *reinterpret_cast<const float4*>(prow + 4);
      s16x8 pa;
      pa[0] = (short)f2bf(p0.x); pa[1] = (short)f2bf(p0.y);
      pa[2] = (short)f2bf(p0.z); pa[3] = (short)f2bf(p0.w);
      pa[4] = (short)f2bf(p1.x); pa[5] = (short)f2bf(p1.y);
      pa[6] = (short)f2bf(p1.z); pa[7] = (short)f2bf(p1.w);
#pragma unroll
      for (int nf = 0; nf < 4; ++nf) {
        const int dd = 16 * nf + lr;
        const s16x8 bv_ = *reinterpret_cast<const s16x8*>(
            vsb + ((dd * 128 + 16 * (lg + 4 * ks)) ^ ((dd & 7) << 4)));
        Oa[nf] = mfma16(pa, bv_, Oa[nf]);
      }
    }

    // rel-v window: O[t] += sum_w P~[t][t-4+w] * ev[w]
    if (diag) {
#pragma unroll
      for (int r = 0; r < 4; ++r) {
        const int tl = 16 * wid + 4 * lg + r;
        const int tg = tc + tl;
#pragma unroll
        for (int w = 0; w < 9; ++w) {
          const int sl_ = tg - 4 + w - s0;
          if (sl_ >= 0 && sl_ < 64) {
            const float p = Ps[wid][(4 * lg + r) * 68 + sl_];
#pragma unroll
            for (int nf = 0; nf < 4; ++nf)
              Oa[nf][r] += p * evs[w][16 * nf + lr];
          }
        }
      }
    }
  }

#pragma unroll
  for (int nf = 0; nf < 4; ++nf) {
#pragma unroll
    for (int r = 0; r < 4; ++r) {
      const int tl = 16 * wid + 4 * lg + r;
      const float val = Oa[nf][r] / lsum[r];
      attb[(bh * T + tc + tl) * 64 + 16 * nf + lr] = f2bf(val);
    }
  }
}

// ---------------------------------------------------------------------------
// Output projection: out[b][o][t] = sum_c Wo[o][c] att[b][h(c)][t][dd(c)] + bo
// A = Wo direct-global; B = att rows copied straight (no transpose).
// ---------------------------------------------------------------------------
__global__ __launch_bounds__(256) void out_gemm(
    const u16* __restrict__ Wob, const float* __restrict__ bo,
    const u16* __restrict__ attb, float* __restrict__ out) {
  __shared__ u16 Bs[2][128 * 32];
  __shared__ float sbias[64];
  const int tid = threadIdx.x;
  const int b = blockIdx.z;
  const int o0 = blockIdx.y * 64;
  const int t0 = blockIdx.x * 128;
  if (tid < 16)
    *reinterpret_cast<float4*>(&sbias[tid * 4]) =
        *reinterpret_cast<const float4*>(&bo[o0 + tid * 4]);

  const int l = tid & 63, wid = tid >> 6;
  const int wm = wid >> 1, wn = wid & 1;
  const int lr = l & 15, lg = l >> 4;

  const int slot = tid & 3, trow = tid >> 2;  // 64 t-rows per rep
  const u16* Arow0 = Wob + (size_t)(o0 + 32 * wm + lr) * C + 8 * lg;
  const u16* Arow1 = Arow0 + 16 * C;

  f32x4 acc[2][4] = {};

  auto stage = [&](int kk, int buf) {
    const int c0 = kk * 32;
    const int h = c0 >> 6, dd0 = c0 & 63;
    char* base = (char*)&Bs[buf][0];
#pragma unroll
    for (int rep = 0; rep < 2; ++rep) {
      const int t = rep * 64 + trow;
      const u16x8 v = *reinterpret_cast<const u16x8*>(
          &attb[((size_t)((b * 8 + h) * T) + t0 + t) * 64 + dd0 + 8 * slot]);
      *(u16x8*)(base + ((t * 64 + 16 * slot) ^ ((t & 3) << 4))) = v;
    }
  };

  s16x8 a0 = *reinterpret_cast<const s16x8*>(Arow0);
  s16x8 a1 = *reinterpret_cast<const s16x8*>(Arow1);
  stage(0, 0);
  __syncthreads();

  for (int kk = 0; kk < 16; ++kk) {
    s16x8 an0, an1;
    if (kk < 15) {
      an0 = *reinterpret_cast<const s16x8*>(Arow0 + (kk + 1) * 32);
      an1 = *reinterpret_cast<const s16x8*>(Arow1 + (kk + 1) * 32);
      stage(kk + 1, (kk + 1) & 1);
    }
    const char* rb = (const char*)&Bs[kk & 1][0];
#pragma unroll
    for (int nf = 0; nf < 4; ++nf) {
      const int t = 64 * wn + 16 * nf + lr;
      const s16x8 bfrag = *reinterpret_cast<const s16x8*>(
          rb + ((t * 64 + 16 * lg) ^ ((t & 3) << 4)));
      acc[0][nf] = mfma16(a0, bfrag, acc[0][nf]);
      acc[1][nf] = mfma16(a1, bfrag, acc[1][nf]);
    }
    __syncthreads();
    if (kk < 15) { a0 = an0; a1 = an1; }
  }

#pragma unroll
  for (int m = 0; m < 2; ++m) {
    const int ol = 32 * wm + 16 * m + 4 * lg;
#pragma unroll
    for (int nf = 0; nf < 4; ++nf) {
      const int t = t0 + 64 * wn + 16 * nf + lr;
#pragma unroll
      for (int r = 0; r < 4; ++r)
        out[((size_t)(b * C) + o0 + ol + r) * T + t] =
            acc[m][nf][r] + sbias[ol + r];
    }
  }
}

}  // namespace

extern "C" void kernel_launch(void* const* d_in, const int* in_sizes, int n_in,
                              void* d_out, int out_size, void* d_ws,
                              size_t ws_size, hipStream_t stream) {
  const float* x    = (const float*)d_in[0];
  const int*   mask = (const int*)d_in[1];
  const float* Wq   = (const float*)d_in[2];
  const float* bq   = (const float*)d_in[3];
  const float* Wk   = (const float*)d_in[4];
  const float* bk   = (const float*)d_in[5];
  const float* Wv   = (const float*)d_in[6];
  const float* bv   = (const float*)d_in[7];
  const float* Wo   = (const float*)d_in[8];
  const float* bo   = (const float*)d_in[9];
  const float* ek   = (const float*)d_in[10];
  const float* ev   = (const float*)d_in[11];
  float* out = (float*)d_out;

  char* ws = (char*)d_ws;
  u16* xb   = (u16*)(ws);                    // 4 MB  [B][C][T]
  u16* Wqb  = (u16*)(ws + 4194304);          // 512 KB each
  u16* Wkb  = (u16*)(ws + 4718592);
  u16* Wvb  = (u16*)(ws + 5242880);
  u16* Wob  = (u16*)(ws + 5767168);
  u16* qb   = (u16*)(ws + 6291456);          // 4 MB  [B][H][T][64]
  u16* kb   = (u16*)(ws + 10485760);         // 4 MB  [B][H][T][64]
  u16* vb   = (u16*)(ws + 14680064);         // 4 MB  [B][H][64][T]
  u16* attb = (u16*)(ws + 18874368);         // 4 MB  [B][H][T][64]

  convert_all<<<dim3(3072), dim3(256), 0, stream>>>(x, Wq, Wk, Wv, Wo, xb, Wqb,
                                                    Wkb, Wvb, Wob);
  qkv_gemm<<<dim3(8, 8, 12), dim3(256), 0, stream>>>(xb, Wqb, Wkb, Wvb, bq, bk,
                                                     bv, qb, kb, vb);
  attn_mfma<<<dim3(16, 8, 4), dim3(256), 0, stream>>>(qb, kb, vb, mask, ek, ev,
                                                      attb);
  out_gemm<<<dim3(8, 8, 4), dim3(256), 0, stream>>>(Wob, bo, attb, out);
}